// Round 2
// baseline (492.356 us; speedup 1.0000x reference)
//
#include <hip/hip_runtime.h>
#include <stdint.h>

#define BSZ 4
#define SEQ 1024
#define EMB 1024
#define NH 16
#define HD 64

static constexpr float kScaling   = 0.125f;               // 64^-0.5
static constexpr float kAttnConst = 3.032639477052158f;

using u16 = unsigned short;
typedef __attribute__((ext_vector_type(8))) short  frag8;   // 8 x bf16 (4 VGPR)
typedef __attribute__((ext_vector_type(4))) float  floatx4; // MFMA C/D
typedef __attribute__((ext_vector_type(4))) u16    u16x4;

__device__ inline float bf2f(u16 v) {
  uint32_t u = ((uint32_t)v) << 16;
  return __builtin_bit_cast(float, u);
}
__device__ inline u16 f2bf(float x) {
  uint32_t u = __builtin_bit_cast(uint32_t, x);
  u += 0x7fffu + ((u >> 16) & 1u);   // RNE
  return (u16)(u >> 16);
}

// ---------------------------------------------------------------------------
// K0: fp32 -> bf16 convert of hidden (4M) + Wq/Wk/Wv/Wo (1M each).
// ---------------------------------------------------------------------------
__global__ __launch_bounds__(256)
void cvt_kernel(const float* __restrict__ H,
                const float* __restrict__ Wq, const float* __restrict__ Wk,
                const float* __restrict__ Wv, const float* __restrict__ Wo,
                u16* __restrict__ Xb,
                u16* __restrict__ Wqb, u16* __restrict__ Wkb,
                u16* __restrict__ Wvb, u16* __restrict__ Wob)
{
  const size_t base = ((size_t)blockIdx.x * 256 + threadIdx.x) * 4;
  const size_t HN = (size_t)BSZ * SEQ * EMB;      // 4M
  const size_t WN = (size_t)EMB * EMB;            // 1M
  const float* src;
  u16* dst;
  size_t off;
  if (base < HN) {
    src = H; dst = Xb; off = base;
  } else {
    const size_t r = base - HN;
    const int w = (int)(r >> 20);                 // WN = 2^20
    off = r & (WN - 1);
    src = (w == 0) ? Wq : (w == 1) ? Wk : (w == 2) ? Wv : Wo;
    dst = (w == 0) ? Wqb : (w == 1) ? Wkb : (w == 2) ? Wvb : Wob;
  }
  const float4 v = *reinterpret_cast<const float4*>(src + off);
  u16x4 o;
  o[0] = f2bf(v.x); o[1] = f2bf(v.y); o[2] = f2bf(v.z); o[3] = f2bf(v.w);
  *reinterpret_cast<u16x4*>(dst + off) = o;
}

// ---------------------------------------------------------------------------
// 128x128 NT GEMM mainloop (m97 structure), bf16 operands.
// ---------------------------------------------------------------------------
__device__ inline void gemm_mainloop(const u16* __restrict__ X,
                                     const u16* __restrict__ W,
                                     int m0, int n0,
                                     u16* As, u16* Bs,
                                     floatx4 acc[4][4])
{
  const int tid  = threadIdx.x;
  const int wave = tid >> 6;
  const int lane = tid & 63;
  const int l15  = lane & 15;
  const int quad = lane >> 4;
  const int wr   = (wave >> 1) * 64;
  const int wc   = (wave & 1) * 64;
  const int srow = wave * 32 + (lane >> 3);
  const int scol = (lane & 7) * 8;

  for (int i = 0; i < 4; ++i)
    for (int j = 0; j < 4; ++j)
      acc[i][j] = (floatx4){0.f, 0.f, 0.f, 0.f};

  for (int k0 = 0; k0 < EMB; k0 += 64) {
    for (int i = 0; i < 4; ++i) {
      const u16* ga = X + (size_t)(m0 + srow + i * 8) * EMB + k0 + scol;
      const u16* gb = W + (size_t)(n0 + srow + i * 8) * EMB + k0 + scol;
      u16* la = As + (wave * 4 + i) * 512;
      u16* lb = Bs + (wave * 4 + i) * 512;
      __builtin_amdgcn_global_load_lds(
          (__attribute__((address_space(1))) void*)ga,
          (__attribute__((address_space(3))) void*)la, 16, 0, 0);
      __builtin_amdgcn_global_load_lds(
          (__attribute__((address_space(1))) void*)gb,
          (__attribute__((address_space(3))) void*)lb, 16, 0, 0);
    }
    __syncthreads();
    for (int kc = 0; kc < 2; ++kc) {
      frag8 af[4], bfr[4];
      for (int i = 0; i < 4; ++i)
        af[i] = *reinterpret_cast<const frag8*>(
            As + (wr + i * 16 + l15) * 64 + kc * 32 + quad * 8);
      for (int j = 0; j < 4; ++j)
        bfr[j] = *reinterpret_cast<const frag8*>(
            Bs + (wc + j * 16 + l15) * 64 + kc * 32 + quad * 8);
      for (int i = 0; i < 4; ++i)
        for (int j = 0; j < 4; ++j)
          acc[i][j] = __builtin_amdgcn_mfma_f32_16x16x32_bf16(
              af[i], bfr[j], acc[i][j], 0, 0, 0);
    }
    __syncthreads();
  }
}

// ---------------------------------------------------------------------------
// K1: QKV projections. z=0 -> Q (scaled), z=1 -> K, z=2 -> Vt[bh][d][t].
// ---------------------------------------------------------------------------
__global__ __launch_bounds__(256, 3)
void qkv_kernel(const u16* __restrict__ X,
                const u16* __restrict__ Wqb, const float* __restrict__ bq,
                const u16* __restrict__ Wkb, const float* __restrict__ bk,
                const u16* __restrict__ Wvb, const float* __restrict__ bv,
                u16* __restrict__ Qs, u16* __restrict__ Ks, u16* __restrict__ Vt)
{
  __shared__ __align__(16) u16 As[128 * 64];
  __shared__ __align__(16) u16 Bs[128 * 64];
  const int z  = blockIdx.z;
  const u16*   W  = (z == 0) ? Wqb : (z == 1) ? Wkb : Wvb;
  const float* bb = (z == 0) ? bq  : (z == 1) ? bk  : bv;
  const int m0 = blockIdx.y * 128;
  const int n0 = blockIdx.x * 128;

  floatx4 acc[4][4];
  gemm_mainloop(X, W, m0, n0, As, Bs, acc);

  const int lane = threadIdx.x & 63, l15 = lane & 15, quad = lane >> 4;
  const int wave = threadIdx.x >> 6;
  const int wr = (wave >> 1) * 64, wc = (wave & 1) * 64;

  for (int j = 0; j < 4; ++j) {
    const int   n  = n0 + wc + j * 16 + l15;
    const float bn = bb[n];
    for (int i = 0; i < 4; ++i) {
      const int mbase = m0 + wr + i * 16 + quad * 4;
      if (z == 2) {
        const int b = mbase >> 10, t = mbase & 1023;
        const int h = n >> 6,      d = n & 63;
        u16x4 pk;
        for (int r = 0; r < 4; ++r) pk[r] = f2bf(acc[i][j][r] + bn);
        *reinterpret_cast<u16x4*>(
            Vt + ((size_t)((b * NH + h) * HD + d)) * SEQ + t) = pk;
      } else {
        u16* dst = (z == 0) ? Qs : Ks;
        const float sc = (z == 0) ? kScaling : 1.0f;
        for (int r = 0; r < 4; ++r)
          dst[(size_t)(mbase + r) * EMB + n] = f2bf((acc[i][j][r] + bn) * sc);
      }
    }
  }
}

// ---------------------------------------------------------------------------
// K2: attention per (b,h). 128 q-rows/block (16/wave, 8 waves, 512 thr),
// 64-key tiles. Grid (64,8) = 512 blocks = exactly 2/CU, no tail.
// No-max softmax (scores bounded: |s|<~20 << 85 fp32-exp limit).
//
// Bias path (the 256 MB mandatory stream): staged per tile into LDS via
// float4 global_load_lds (16 B/lane coalesced) instead of 16 scalar 4 B
// loads/thread/tile. LDS layout XOR-swizzled, key(row)=((row>>2)&3)<<4
// f32-units (=64 B, multiple of the 16 B DMA granule). Source address is
// pre-XORed with the same key (both-sides-or-neither rule): within a row,
// staging covers cols ((lane&15)*4)^(p<<4), bijective per row. Readback
// ds_read_b32 at col^(quad<<4): 16 lanes x 4 quads -> 2 lanes/bank = free.
//
// LDS: Kt 8K + Vs 8K + Pbuf 16K + Bf 32K = exactly 64 KB; 2 blocks/CU.
// ---------------------------------------------------------------------------
__global__ __launch_bounds__(512, 4)
void attn_kernel(const u16* __restrict__ Qs, const u16* __restrict__ Ks,
                 const u16* __restrict__ Vt, const float* __restrict__ bias,
                 u16* __restrict__ ctx)
{
  __shared__ __align__(16) u16   Kt[64 * 64];
  __shared__ __align__(16) u16   Vs[64 * 64];
  __shared__ __align__(16) u16   Pbuf[128 * 64];   // XOR-swizzled, stride 64
  __shared__ __align__(16) float Bf[128 * 64];     // bias tile, swizzled f32
  const int bh = blockIdx.x;
  const int b  = bh >> 4;
  const int h  = bh & 15;
  const int t0 = blockIdx.y * 128;
  const int wave = threadIdx.x >> 6;               // 0..7
  const int lane = threadIdx.x & 63;
  const int l15 = lane & 15, quad = lane >> 4;
  const int wrow = t0 + wave * 16;
  const int srow = wave * 8 + (lane >> 3);         // K/V staging row
  const int scol = (lane & 7) * 8;

  // Q A-frags (A[m=l15][k=quad*8+j]) held in registers for the whole kernel
  frag8 qf[2];
  for (int kc = 0; kc < 2; ++kc)
    qf[kc] = *reinterpret_cast<const frag8*>(
        Qs + (size_t)(b * SEQ + wrow + l15) * EMB + h * HD + kc * 32 + quad * 8);

  floatx4 O[4];
  for (int df = 0; df < 4; ++df) O[df] = (floatx4){0.f, 0.f, 0.f, 0.f};
  float rs[4] = {0.f, 0.f, 0.f, 0.f};

  const float* bias_bh = bias + (size_t)bh * SEQ * SEQ;

  for (int s0 = 0; s0 < SEQ; s0 += 64) {
    // ---- stage K tile (keys x d) and V tile (d x keys) : 1 instr each/wave
    {
      const u16* gk = Ks + (size_t)(b * SEQ + s0 + srow) * EMB + h * HD + scol;
      const u16* gv = Vt + ((size_t)bh * HD + srow) * SEQ + s0 + scol;
      __builtin_amdgcn_global_load_lds(
          (__attribute__((address_space(1))) void*)gk,
          (__attribute__((address_space(3))) void*)(Kt + wave * 512), 16, 0, 0);
      __builtin_amdgcn_global_load_lds(
          (__attribute__((address_space(1))) void*)gv,
          (__attribute__((address_space(3))) void*)(Vs + wave * 512), 16, 0, 0);
    }
    // ---- stage bias tile 128x64 f32 (32 KB): 4 float4 DMA per thread.
    // wave w, pass p covers rows (w*4+p)*4 + (lane>>4); within-row source
    // col pre-XORed with key = p<<4 (f32 units) so the linear LDS write
    // lands the swizzled layout.
    for (int p = 0; p < 4; ++p) {
      const int row = (wave * 4 + p) * 4 + (lane >> 4);
      const int col = ((lane & 15) * 4) ^ (p << 4);
      const float* gsrc = bias_bh + (size_t)(t0 + row) * SEQ + s0 + col;
      __builtin_amdgcn_global_load_lds(
          (__attribute__((address_space(1))) void*)gsrc,
          (__attribute__((address_space(3))) void*)(Bf + (wave * 4 + p) * 256),
          16, 0, 0);
    }
    __syncthreads();   // K/V/bias tiles resident

    // ---- S = Q K^T
    floatx4 S[4];
    __builtin_amdgcn_s_setprio(1);
    for (int nf = 0; nf < 4; ++nf) {
      frag8 k0f = *reinterpret_cast<const frag8*>(
          Kt + (nf * 16 + l15) * 64 + quad * 8);
      frag8 k1f = *reinterpret_cast<const frag8*>(
          Kt + (nf * 16 + l15) * 64 + 32 + quad * 8);
      floatx4 a0 = __builtin_amdgcn_mfma_f32_16x16x32_bf16(
          qf[0], k0f, (floatx4){0.f, 0.f, 0.f, 0.f}, 0, 0, 0);
      S[nf] = __builtin_amdgcn_mfma_f32_16x16x32_bf16(qf[1], k1f, a0, 0, 0, 0);
    }
    __builtin_amdgcn_s_setprio(0);

    // ---- bias from LDS (swizzled, conflict-free), p = exp(s + c*bias)
    for (int nf = 0; nf < 4; ++nf)
      for (int r = 0; r < 4; ++r) {
        const float bvv = Bf[(wave * 16 + quad * 4 + r) * 64 +
                             ((nf * 16 + l15) ^ (quad << 4))];
        const float p = __expf(fmaf(kAttnConst, bvv, S[nf][r]));
        rs[r] += p;
        Pbuf[(wave * 16 + quad * 4 + r) * 64 + ((nf * 16 + l15) ^ (quad << 4))] =
            f2bf(p);
      }
    asm volatile("s_waitcnt lgkmcnt(0)" ::: "memory");  // wave-private P ready

    // ---- O += P @ V  (readback applies the same per-row XOR key)
    frag8 pa[2];
    for (int sc = 0; sc < 2; ++sc)
      pa[sc] = *reinterpret_cast<const frag8*>(
          Pbuf + (wave * 16 + l15) * 64 +
          ((sc * 32 + quad * 8) ^ ((l15 >> 2) << 4)));
    __builtin_amdgcn_s_setprio(1);
    for (int df = 0; df < 4; ++df) {
      frag8 v0f = *reinterpret_cast<const frag8*>(
          Vs + (df * 16 + l15) * 64 + quad * 8);
      frag8 v1f = *reinterpret_cast<const frag8*>(
          Vs + (df * 16 + l15) * 64 + 32 + quad * 8);
      O[df] = __builtin_amdgcn_mfma_f32_16x16x32_bf16(pa[0], v0f, O[df], 0, 0, 0);
      O[df] = __builtin_amdgcn_mfma_f32_16x16x32_bf16(pa[1], v1f, O[df], 0, 0, 0);
    }
    __builtin_amdgcn_s_setprio(0);
    __syncthreads();   // all LDS reads done before next stage overwrites
  }

  // ---- single cross-lane reduce of row sums (over the 16 cols per quad)
  for (int d = 1; d < 16; d <<= 1)
    for (int r = 0; r < 4; ++r)
      rs[r] += __shfl_xor(rs[r], d);

  for (int df = 0; df < 4; ++df)
    for (int r = 0; r < 4; ++r) {
      const int t = wrow + quad * 4 + r;
      ctx[((size_t)(b * SEQ + t)) * EMB + h * HD + df * 16 + l15] =
          f2bf(O[df][r] / rs[r]);
    }
}

// ---------------------------------------------------------------------------
// K3: out = ctx @ Wo^T + bo  (fp32 out). BM=64 x BN=128 -> 512 blocks.
// ---------------------------------------------------------------------------
__global__ __launch_bounds__(256, 4)
void proj_kernel(const u16* __restrict__ X, const u16* __restrict__ Wob,
                 const float* __restrict__ bo, float* __restrict__ out)
{
  __shared__ __align__(16) u16 As[64 * 64];
  __shared__ __align__(16) u16 Bs[128 * 64];
  const int m0 = blockIdx.y * 64;
  const int n0 = blockIdx.x * 128;

  const int tid  = threadIdx.x;
  const int wave = tid >> 6;
  const int lane = tid & 63;
  const int l15  = lane & 15;
  const int quad = lane >> 4;
  const int wr   = (wave >> 1) * 32;          // 2x2 waves of 32x64
  const int wc   = (wave & 1) * 64;
  const int srowA = wave * 16 + (lane >> 3);  // + i*8, i<2
  const int srowB = wave * 32 + (lane >> 3);  // + i*8, i<4
  const int scol  = (lane & 7) * 8;

  floatx4 acc[2][4];
  for (int i = 0; i < 2; ++i)
    for (int j = 0; j < 4; ++j)
      acc[i][j] = (floatx4){0.f, 0.f, 0.f, 0.f};

  for (int k0 = 0; k0 < EMB; k0 += 64) {
    for (int i = 0; i < 2; ++i) {
      const u16* ga = X + (size_t)(m0 + srowA + i * 8) * EMB + k0 + scol;
      __builtin_amdgcn_global_load_lds(
          (__attribute__((address_space(1))) void*)ga,
          (__attribute__((address_space(3))) void*)(As + (wave * 2 + i) * 512),
          16, 0, 0);
    }
    for (int i = 0; i < 4; ++i) {
      const u16* gb = Wob + (size_t)(n0 + srowB + i * 8) * EMB + k0 + scol;
      __builtin_amdgcn_global_load_lds(
          (__attribute__((address_space(1))) void*)gb,
          (__attribute__((address_space(3))) void*)(Bs + (wave * 4 + i) * 512),
          16, 0, 0);
    }
    __syncthreads();
    for (int kc = 0; kc < 2; ++kc) {
      frag8 af[2], bfr[4];
      for (int i = 0; i < 2; ++i)
        af[i] = *reinterpret_cast<const frag8*>(
            As + (wr + i * 16 + l15) * 64 + kc * 32 + quad * 8);
      for (int j = 0; j < 4; ++j)
        bfr[j] = *reinterpret_cast<const frag8*>(
            Bs + (wc + j * 16 + l15) * 64 + kc * 32 + quad * 8);
      for (int i = 0; i < 2; ++i)
        for (int j = 0; j < 4; ++j)
          acc[i][j] = __builtin_amdgcn_mfma_f32_16x16x32_bf16(
              af[i], bfr[j], acc[i][j], 0, 0, 0);
    }
    __syncthreads();
  }

  for (int j = 0; j < 4; ++j) {
    const int   n  = n0 + wc + j * 16 + l15;
    const float bn = bo[n];
    for (int i = 0; i < 2; ++i) {
      const int mbase = m0 + wr + i * 16 + quad * 4;
      for (int r = 0; r < 4; ++r)
        out[(size_t)(mbase + r) * EMB + n] = acc[i][j][r] + bn;
    }
  }
}

// ---------------------------------------------------------------------------
extern "C" void kernel_launch(void* const* d_in, const int* in_sizes, int n_in,
                              void* d_out, int out_size, void* d_ws, size_t ws_size,
                              hipStream_t stream)
{
  const float* hidden = (const float*)d_in[0];
  const float* attn_b = (const float*)d_in[1];
  const float* Wq = (const float*)d_in[2];
  const float* bq = (const float*)d_in[3];
  const float* Wk = (const float*)d_in[4];
  const float* bk = (const float*)d_in[5];
  const float* Wv = (const float*)d_in[6];
  const float* bv = (const float*)d_in[7];
  const float* Wo = (const float*)d_in[8];
  const float* bo = (const float*)d_in[9];
  float* out = (float*)d_out;

  const size_t MAT = (size_t)BSZ * SEQ * EMB;   // 4M elems
  const size_t WN  = (size_t)EMB * EMB;         // 1M elems
  u16* Qs  = (u16*)d_ws;
  u16* Ks  = Qs + MAT;
  u16* Vt  = Ks + MAT;
  u16* ctx = Vt + MAT;
  u16* Xb  = ctx + MAT;
  u16* Wqb = Xb + MAT;
  u16* Wkb = Wqb + WN;
  u16* Wvb = Wkb + WN;
  u16* Wob = Wvb + WN;            // total 24M u16 = 48 MB

  cvt_kernel<<<8192, 256, 0, stream>>>(hidden, Wq, Wk, Wv, Wo,
                                       Xb, Wqb, Wkb, Wvb, Wob);
  qkv_kernel<<<dim3(8, 32, 3), 256, 0, stream>>>(Xb, Wqb, bq, Wkb, bk, Wvb, bv,
                                                 Qs, Ks, Vt);
  attn_kernel<<<dim3(64, 8), 512, 0, stream>>>(Qs, Ks, Vt, attn_b, ctx);
  proj_kernel<<<dim3(8, 64), 256, 0, stream>>>(ctx, Wob, bo, out);
}

// Round 3
// 468.003 us; speedup vs baseline: 1.0520x; 1.0520x over previous
//
#include <hip/hip_runtime.h>
#include <stdint.h>

#define BSZ 4
#define SEQ 1024
#define EMB 1024
#define NH 16
#define HD 64

static constexpr float kScaling   = 0.125f;               // 64^-0.5
static constexpr float kAttnConst = 3.032639477052158f;

using u16 = unsigned short;
typedef __attribute__((ext_vector_type(8))) short  frag8;   // 8 x bf16 (4 VGPR)
typedef __attribute__((ext_vector_type(4))) float  floatx4; // MFMA C/D
typedef __attribute__((ext_vector_type(4))) u16    u16x4;

__device__ inline float bf2f(u16 v) {
  uint32_t u = ((uint32_t)v) << 16;
  return __builtin_bit_cast(float, u);
}
__device__ inline u16 f2bf(float x) {
  uint32_t u = __builtin_bit_cast(uint32_t, x);
  u += 0x7fffu + ((u >> 16) & 1u);   // RNE
  return (u16)(u >> 16);
}

// ---------------------------------------------------------------------------
// K0: fp32 -> bf16 convert of hidden (4M) + Wq/Wk/Wv/Wo (1M each).
// ---------------------------------------------------------------------------
__global__ __launch_bounds__(256)
void cvt_kernel(const float* __restrict__ H,
                const float* __restrict__ Wq, const float* __restrict__ Wk,
                const float* __restrict__ Wv, const float* __restrict__ Wo,
                u16* __restrict__ Xb,
                u16* __restrict__ Wqb, u16* __restrict__ Wkb,
                u16* __restrict__ Wvb, u16* __restrict__ Wob)
{
  const size_t base = ((size_t)blockIdx.x * 256 + threadIdx.x) * 4;
  const size_t HN = (size_t)BSZ * SEQ * EMB;      // 4M
  const size_t WN = (size_t)EMB * EMB;            // 1M
  const float* src;
  u16* dst;
  size_t off;
  if (base < HN) {
    src = H; dst = Xb; off = base;
  } else {
    const size_t r = base - HN;
    const int w = (int)(r >> 20);                 // WN = 2^20
    off = r & (WN - 1);
    src = (w == 0) ? Wq : (w == 1) ? Wk : (w == 2) ? Wv : Wo;
    dst = (w == 0) ? Wqb : (w == 1) ? Wkb : (w == 2) ? Wvb : Wob;
  }
  const float4 v = *reinterpret_cast<const float4*>(src + off);
  u16x4 o;
  o[0] = f2bf(v.x); o[1] = f2bf(v.y); o[2] = f2bf(v.z); o[3] = f2bf(v.w);
  *reinterpret_cast<u16x4*>(dst + off) = o;
}

// ---------------------------------------------------------------------------
// 128x128 NT GEMM mainloop (m97 structure), bf16 operands.
// ---------------------------------------------------------------------------
__device__ inline void gemm_mainloop(const u16* __restrict__ X,
                                     const u16* __restrict__ W,
                                     int m0, int n0,
                                     u16* As, u16* Bs,
                                     floatx4 acc[4][4])
{
  const int tid  = threadIdx.x;
  const int wave = tid >> 6;
  const int lane = tid & 63;
  const int l15  = lane & 15;
  const int quad = lane >> 4;
  const int wr   = (wave >> 1) * 64;
  const int wc   = (wave & 1) * 64;
  const int srow = wave * 32 + (lane >> 3);
  const int scol = (lane & 7) * 8;

  for (int i = 0; i < 4; ++i)
    for (int j = 0; j < 4; ++j)
      acc[i][j] = (floatx4){0.f, 0.f, 0.f, 0.f};

  for (int k0 = 0; k0 < EMB; k0 += 64) {
    for (int i = 0; i < 4; ++i) {
      const u16* ga = X + (size_t)(m0 + srow + i * 8) * EMB + k0 + scol;
      const u16* gb = W + (size_t)(n0 + srow + i * 8) * EMB + k0 + scol;
      u16* la = As + (wave * 4 + i) * 512;
      u16* lb = Bs + (wave * 4 + i) * 512;
      __builtin_amdgcn_global_load_lds(
          (__attribute__((address_space(1))) void*)ga,
          (__attribute__((address_space(3))) void*)la, 16, 0, 0);
      __builtin_amdgcn_global_load_lds(
          (__attribute__((address_space(1))) void*)gb,
          (__attribute__((address_space(3))) void*)lb, 16, 0, 0);
    }
    __syncthreads();
    for (int kc = 0; kc < 2; ++kc) {
      frag8 af[4], bfr[4];
      for (int i = 0; i < 4; ++i)
        af[i] = *reinterpret_cast<const frag8*>(
            As + (wr + i * 16 + l15) * 64 + kc * 32 + quad * 8);
      for (int j = 0; j < 4; ++j)
        bfr[j] = *reinterpret_cast<const frag8*>(
            Bs + (wc + j * 16 + l15) * 64 + kc * 32 + quad * 8);
      for (int i = 0; i < 4; ++i)
        for (int j = 0; j < 4; ++j)
          acc[i][j] = __builtin_amdgcn_mfma_f32_16x16x32_bf16(
              af[i], bfr[j], acc[i][j], 0, 0, 0);
    }
    __syncthreads();
  }
}

// ---------------------------------------------------------------------------
// K1: QKV projections. z=0 -> Q (scaled), z=1 -> K, z=2 -> Vt[bh][d][t].
// ---------------------------------------------------------------------------
__global__ __launch_bounds__(256, 3)
void qkv_kernel(const u16* __restrict__ X,
                const u16* __restrict__ Wqb, const float* __restrict__ bq,
                const u16* __restrict__ Wkb, const float* __restrict__ bk,
                const u16* __restrict__ Wvb, const float* __restrict__ bv,
                u16* __restrict__ Qs, u16* __restrict__ Ks, u16* __restrict__ Vt)
{
  __shared__ __align__(16) u16 As[128 * 64];
  __shared__ __align__(16) u16 Bs[128 * 64];
  const int z  = blockIdx.z;
  const u16*   W  = (z == 0) ? Wqb : (z == 1) ? Wkb : Wvb;
  const float* bb = (z == 0) ? bq  : (z == 1) ? bk  : bv;
  const int m0 = blockIdx.y * 128;
  const int n0 = blockIdx.x * 128;

  floatx4 acc[4][4];
  gemm_mainloop(X, W, m0, n0, As, Bs, acc);

  const int lane = threadIdx.x & 63, l15 = lane & 15, quad = lane >> 4;
  const int wave = threadIdx.x >> 6;
  const int wr = (wave >> 1) * 64, wc = (wave & 1) * 64;

  for (int j = 0; j < 4; ++j) {
    const int   n  = n0 + wc + j * 16 + l15;
    const float bn = bb[n];
    for (int i = 0; i < 4; ++i) {
      const int mbase = m0 + wr + i * 16 + quad * 4;
      if (z == 2) {
        const int b = mbase >> 10, t = mbase & 1023;
        const int h = n >> 6,      d = n & 63;
        u16x4 pk;
        for (int r = 0; r < 4; ++r) pk[r] = f2bf(acc[i][j][r] + bn);
        *reinterpret_cast<u16x4*>(
            Vt + ((size_t)((b * NH + h) * HD + d)) * SEQ + t) = pk;
      } else {
        u16* dst = (z == 0) ? Qs : Ks;
        const float sc = (z == 0) ? kScaling : 1.0f;
        for (int r = 0; r < 4; ++r)
          dst[(size_t)(mbase + r) * EMB + n] = f2bf((acc[i][j][r] + bn) * sc);
      }
    }
  }
}

// ---------------------------------------------------------------------------
// K2: attention per (b,h). 64 q-rows/block (16/wave, 4 waves), 64-key tiles,
// grid (64,16) = 1024 blocks = 4/CU (LDS exactly 40 KB/block).
//
// T3-minimum 2-phase pipeline: K/V double-buffered in LDS; tile t+1's
// stage (global_load_lds) AND tile t+1's bias register-prefetch are issued
// at the TOP of tile t, so the single vmcnt-drain+barrier per tile lands
// after a full tile of MFMA/exp compute has covered the HBM latency.
// (Round-2's single-buffered stage -> drain -> compute chain exposed the
// full latency every tile and regressed; this inverts it.)
//
// No-max softmax (scores bounded; fp32 exp headroom). Pbuf XOR-swizzled
// (key(row) = ((row>>2)&3)<<4 u16-units): write = 2 lanes/bank (free),
// frag8 readback stays 16B-contiguous (key multiple of 16 u16).
// ---------------------------------------------------------------------------
__global__ __launch_bounds__(256, 4)
void attn_kernel(const u16* __restrict__ Qs, const u16* __restrict__ Ks,
                 const u16* __restrict__ Vt, const float* __restrict__ bias,
                 u16* __restrict__ ctx)
{
  __shared__ __align__(16) u16 Kt[2][64 * 64];   // 16 KB
  __shared__ __align__(16) u16 Vs[2][64 * 64];   // 16 KB
  __shared__ __align__(16) u16 Pbuf[64 * 64];    // 8 KB, XOR-swizzled
  const int bh = blockIdx.x;
  const int b  = bh >> 4;
  const int h  = bh & 15;
  const int t0 = blockIdx.y * 64;
  const int wave = threadIdx.x >> 6;
  const int lane = threadIdx.x & 63;
  const int l15 = lane & 15, quad = lane >> 4;
  const int wrow = t0 + wave * 16;
  const int srow = wave * 16 + (lane >> 3);   // staging row (+ i*8)
  const int scol = (lane & 7) * 8;

  // Q A-frags (A[m=l15][k=quad*8+j]) held in registers for the whole kernel
  frag8 qf[2];
  for (int kc = 0; kc < 2; ++kc)
    qf[kc] = *reinterpret_cast<const frag8*>(
        Qs + (size_t)(b * SEQ + wrow + l15) * EMB + h * HD + kc * 32 + quad * 8);

  floatx4 O[4];
  for (int df = 0; df < 4; ++df) O[df] = (floatx4){0.f, 0.f, 0.f, 0.f};
  float rs[4] = {0.f, 0.f, 0.f, 0.f};

  const float* bline = bias + ((size_t)bh * SEQ + wrow + quad * 4) * SEQ + l15;
  const u16* gk_base = Ks + (size_t)(b * SEQ + srow) * EMB + h * HD + scol;
  const u16* gv_base = Vt + ((size_t)bh * HD + srow) * SEQ + scol;

  // ---- prologue: stage tile 0 into buffer 0; prefetch bias tile 0
  for (int i = 0; i < 2; ++i) {
    __builtin_amdgcn_global_load_lds(
        (__attribute__((address_space(1))) void*)(gk_base + (size_t)i * 8 * EMB),
        (__attribute__((address_space(3))) void*)(Kt[0] + (wave * 2 + i) * 512),
        16, 0, 0);
    __builtin_amdgcn_global_load_lds(
        (__attribute__((address_space(1))) void*)(gv_base + i * 8 * SEQ),
        (__attribute__((address_space(3))) void*)(Vs[0] + (wave * 2 + i) * 512),
        16, 0, 0);
  }
  float bc[4][4], bn[4][4];
  for (int nf = 0; nf < 4; ++nf)
    for (int r = 0; r < 4; ++r)
      bc[nf][r] = __builtin_nontemporal_load(bline + (size_t)r * SEQ + nf * 16);
  __syncthreads();   // tile 0 resident

  for (int t = 0; t < 16; ++t) {
    const int c  = t & 1;
    const int s0 = t * 64;

    // ---- issue NEXT tile's stage + bias prefetch (consumed next iteration)
    if (t < 15) {
      const int sn = s0 + 64;
      for (int i = 0; i < 2; ++i) {
        __builtin_amdgcn_global_load_lds(
            (__attribute__((address_space(1))) void*)
                (gk_base + (size_t)(sn + i * 8) * EMB),
            (__attribute__((address_space(3))) void*)
                (Kt[c ^ 1] + (wave * 2 + i) * 512),
            16, 0, 0);
        __builtin_amdgcn_global_load_lds(
            (__attribute__((address_space(1))) void*)
                (gv_base + i * 8 * SEQ + sn),
            (__attribute__((address_space(3))) void*)
                (Vs[c ^ 1] + (wave * 2 + i) * 512),
            16, 0, 0);
      }
      for (int nf = 0; nf < 4; ++nf)
        for (int r = 0; r < 4; ++r)
          bn[nf][r] = __builtin_nontemporal_load(
              bline + (size_t)r * SEQ + sn + nf * 16);
    }

    // ---- S = Q K^T  (reads Kt[c])
    floatx4 S[4];
    __builtin_amdgcn_s_setprio(1);
    for (int nf = 0; nf < 4; ++nf) {
      frag8 k0f = *reinterpret_cast<const frag8*>(
          Kt[c] + (nf * 16 + l15) * 64 + quad * 8);
      frag8 k1f = *reinterpret_cast<const frag8*>(
          Kt[c] + (nf * 16 + l15) * 64 + 32 + quad * 8);
      floatx4 a0 = __builtin_amdgcn_mfma_f32_16x16x32_bf16(
          qf[0], k0f, (floatx4){0.f, 0.f, 0.f, 0.f}, 0, 0, 0);
      S[nf] = __builtin_amdgcn_mfma_f32_16x16x32_bf16(qf[1], k1f, a0, 0, 0, 0);
    }
    __builtin_amdgcn_s_setprio(0);

    // ---- p = exp(s + c*bias) using the prefetched bias registers
    for (int nf = 0; nf < 4; ++nf)
      for (int r = 0; r < 4; ++r) {
        const float p = __expf(fmaf(kAttnConst, bc[nf][r], S[nf][r]));
        rs[r] += p;
        Pbuf[(wave * 16 + quad * 4 + r) * 64 + ((nf * 16 + l15) ^ (quad << 4))] =
            f2bf(p);
      }
    if (t < 15)
      for (int nf = 0; nf < 4; ++nf)
        for (int r = 0; r < 4; ++r) bc[nf][r] = bn[nf][r];
    asm volatile("s_waitcnt lgkmcnt(0)" ::: "memory");  // wave-private P ready

    // ---- O += P @ V  (reads Vs[c]; readback applies the same per-row XOR)
    frag8 pa[2];
    for (int sc = 0; sc < 2; ++sc)
      pa[sc] = *reinterpret_cast<const frag8*>(
          Pbuf + (wave * 16 + l15) * 64 +
          ((sc * 32 + quad * 8) ^ ((l15 >> 2) << 4)));
    __builtin_amdgcn_s_setprio(1);
    for (int df = 0; df < 4; ++df) {
      frag8 v0f = *reinterpret_cast<const frag8*>(
          Vs[c] + (df * 16 + l15) * 64 + quad * 8);
      frag8 v1f = *reinterpret_cast<const frag8*>(
          Vs[c] + (df * 16 + l15) * 64 + 32 + quad * 8);
      O[df] = __builtin_amdgcn_mfma_f32_16x16x32_bf16(pa[0], v0f, O[df], 0, 0, 0);
      O[df] = __builtin_amdgcn_mfma_f32_16x16x32_bf16(pa[1], v1f, O[df], 0, 0, 0);
    }
    __builtin_amdgcn_s_setprio(0);
    // drain: next-tile stage landed in buf[c^1]; all waves done reading buf[c]
    __syncthreads();
  }

  // ---- single cross-lane reduce of row sums (over the 16 cols per quad)
  for (int d = 1; d < 16; d <<= 1)
    for (int r = 0; r < 4; ++r)
      rs[r] += __shfl_xor(rs[r], d);

  for (int df = 0; df < 4; ++df)
    for (int r = 0; r < 4; ++r) {
      const int t = wrow + quad * 4 + r;
      ctx[((size_t)(b * SEQ + t)) * EMB + h * HD + df * 16 + l15] =
          f2bf(O[df][r] / rs[r]);
    }
}

// ---------------------------------------------------------------------------
// K3: out = ctx @ Wo^T + bo  (fp32 out). BM=64 x BN=128 -> 512 blocks.
// ---------------------------------------------------------------------------
__global__ __launch_bounds__(256, 4)
void proj_kernel(const u16* __restrict__ X, const u16* __restrict__ Wob,
                 const float* __restrict__ bo, float* __restrict__ out)
{
  __shared__ __align__(16) u16 As[64 * 64];
  __shared__ __align__(16) u16 Bs[128 * 64];
  const int m0 = blockIdx.y * 64;
  const int n0 = blockIdx.x * 128;

  const int tid  = threadIdx.x;
  const int wave = tid >> 6;
  const int lane = tid & 63;
  const int l15  = lane & 15;
  const int quad = lane >> 4;
  const int wr   = (wave >> 1) * 32;          // 2x2 waves of 32x64
  const int wc   = (wave & 1) * 64;
  const int srowA = wave * 16 + (lane >> 3);  // + i*8, i<2
  const int srowB = wave * 32 + (lane >> 3);  // + i*8, i<4
  const int scol  = (lane & 7) * 8;

  floatx4 acc[2][4];
  for (int i = 0; i < 2; ++i)
    for (int j = 0; j < 4; ++j)
      acc[i][j] = (floatx4){0.f, 0.f, 0.f, 0.f};

  for (int k0 = 0; k0 < EMB; k0 += 64) {
    for (int i = 0; i < 2; ++i) {
      const u16* ga = X + (size_t)(m0 + srowA + i * 8) * EMB + k0 + scol;
      __builtin_amdgcn_global_load_lds(
          (__attribute__((address_space(1))) void*)ga,
          (__attribute__((address_space(3))) void*)(As + (wave * 2 + i) * 512),
          16, 0, 0);
    }
    for (int i = 0; i < 4; ++i) {
      const u16* gb = Wob + (size_t)(n0 + srowB + i * 8) * EMB + k0 + scol;
      __builtin_amdgcn_global_load_lds(
          (__attribute__((address_space(1))) void*)gb,
          (__attribute__((address_space(3))) void*)(Bs + (wave * 4 + i) * 512),
          16, 0, 0);
    }
    __syncthreads();
    for (int kc = 0; kc < 2; ++kc) {
      frag8 af[2], bfr[4];
      for (int i = 0; i < 2; ++i)
        af[i] = *reinterpret_cast<const frag8*>(
            As + (wr + i * 16 + l15) * 64 + kc * 32 + quad * 8);
      for (int j = 0; j < 4; ++j)
        bfr[j] = *reinterpret_cast<const frag8*>(
            Bs + (wc + j * 16 + l15) * 64 + kc * 32 + quad * 8);
      for (int i = 0; i < 2; ++i)
        for (int j = 0; j < 4; ++j)
          acc[i][j] = __builtin_amdgcn_mfma_f32_16x16x32_bf16(
              af[i], bfr[j], acc[i][j], 0, 0, 0);
    }
    __syncthreads();
  }

  for (int j = 0; j < 4; ++j) {
    const int   n  = n0 + wc + j * 16 + l15;
    const float bn = bo[n];
    for (int i = 0; i < 2; ++i) {
      const int mbase = m0 + wr + i * 16 + quad * 4;
      for (int r = 0; r < 4; ++r)
        out[(size_t)(mbase + r) * EMB + n] = acc[i][j][r] + bn;
    }
  }
}

// ---------------------------------------------------------------------------
extern "C" void kernel_launch(void* const* d_in, const int* in_sizes, int n_in,
                              void* d_out, int out_size, void* d_ws, size_t ws_size,
                              hipStream_t stream)
{
  const float* hidden = (const float*)d_in[0];
  const float* attn_b = (const float*)d_in[1];
  const float* Wq = (const float*)d_in[2];
  const float* bq = (const float*)d_in[3];
  const float* Wk = (const float*)d_in[4];
  const float* bk = (const float*)d_in[5];
  const float* Wv = (const float*)d_in[6];
  const float* bv = (const float*)d_in[7];
  const float* Wo = (const float*)d_in[8];
  const float* bo = (const float*)d_in[9];
  float* out = (float*)d_out;

  const size_t MAT = (size_t)BSZ * SEQ * EMB;   // 4M elems
  const size_t WN  = (size_t)EMB * EMB;         // 1M elems
  u16* Qs  = (u16*)d_ws;
  u16* Ks  = Qs + MAT;
  u16* Vt  = Ks + MAT;
  u16* ctx = Vt + MAT;
  u16* Xb  = ctx + MAT;
  u16* Wqb = Xb + MAT;
  u16* Wkb = Wqb + WN;
  u16* Wvb = Wkb + WN;
  u16* Wob = Wvb + WN;            // total 24M u16 = 48 MB

  cvt_kernel<<<8192, 256, 0, stream>>>(hidden, Wq, Wk, Wv, Wo,
                                       Xb, Wqb, Wkb, Wvb, Wob);
  qkv_kernel<<<dim3(8, 32, 3), 256, 0, stream>>>(Xb, Wqb, bq, Wkb, bk, Wvb, bv,
                                                 Qs, Ks, Vt);
  attn_kernel<<<dim3(64, 16), 256, 0, stream>>>(Qs, Ks, Vt, attn_b, ctx);
  proj_kernel<<<dim3(8, 64), 256, 0, stream>>>(ctx, Wob, bo, out);
}

// Round 4
// 465.463 us; speedup vs baseline: 1.0578x; 1.0055x over previous
//
#include <hip/hip_runtime.h>
#include <stdint.h>

#define BSZ 4
#define SEQ 1024
#define EMB 1024
#define NH 16
#define HD 64

static constexpr float kScaling   = 0.125f;               // 64^-0.5
static constexpr float kAttnConst = 3.032639477052158f;

using u16 = unsigned short;
typedef __attribute__((ext_vector_type(8))) short  frag8;   // 8 x bf16 (4 VGPR)
typedef __attribute__((ext_vector_type(4))) float  floatx4; // MFMA C/D
typedef __attribute__((ext_vector_type(4))) u16    u16x4;

__device__ inline float bf2f(u16 v) {
  uint32_t u = ((uint32_t)v) << 16;
  return __builtin_bit_cast(float, u);
}
__device__ inline u16 f2bf(float x) {
  uint32_t u = __builtin_bit_cast(uint32_t, x);
  u += 0x7fffu + ((u >> 16) & 1u);   // RNE
  return (u16)(u >> 16);
}

// ---------------------------------------------------------------------------
// K0: fp32 -> bf16 convert of hidden (4M) + Wq/Wk/Wv/Wo (1M each).
// ---------------------------------------------------------------------------
__global__ __launch_bounds__(256)
void cvt_kernel(const float* __restrict__ H,
                const float* __restrict__ Wq, const float* __restrict__ Wk,
                const float* __restrict__ Wv, const float* __restrict__ Wo,
                u16* __restrict__ Xb,
                u16* __restrict__ Wqb, u16* __restrict__ Wkb,
                u16* __restrict__ Wvb, u16* __restrict__ Wob)
{
  const size_t base = ((size_t)blockIdx.x * 256 + threadIdx.x) * 4;
  const size_t HN = (size_t)BSZ * SEQ * EMB;      // 4M
  const size_t WN = (size_t)EMB * EMB;            // 1M
  const float* src;
  u16* dst;
  size_t off;
  if (base < HN) {
    src = H; dst = Xb; off = base;
  } else {
    const size_t r = base - HN;
    const int w = (int)(r >> 20);                 // WN = 2^20
    off = r & (WN - 1);
    src = (w == 0) ? Wq : (w == 1) ? Wk : (w == 2) ? Wv : Wo;
    dst = (w == 0) ? Wqb : (w == 1) ? Wkb : (w == 2) ? Wvb : Wob;
  }
  const float4 v = *reinterpret_cast<const float4*>(src + off);
  u16x4 o;
  o[0] = f2bf(v.x); o[1] = f2bf(v.y); o[2] = f2bf(v.z); o[3] = f2bf(v.w);
  *reinterpret_cast<u16x4*>(dst + off) = o;
}

// ---------------------------------------------------------------------------
// 128x128 NT GEMM mainloop (m97 structure), bf16 operands.
// As = SM, Bs = SM + 8192 (mainloop uses 32 KB of the 34 KB epilogue buffer).
// ---------------------------------------------------------------------------
__device__ inline void gemm_mainloop(const u16* __restrict__ X,
                                     const u16* __restrict__ W,
                                     int m0, int n0,
                                     u16* As, u16* Bs,
                                     floatx4 acc[4][4])
{
  const int tid  = threadIdx.x;
  const int wave = tid >> 6;
  const int lane = tid & 63;
  const int l15  = lane & 15;
  const int quad = lane >> 4;
  const int wr   = (wave >> 1) * 64;
  const int wc   = (wave & 1) * 64;
  const int srow = wave * 32 + (lane >> 3);
  const int scol = (lane & 7) * 8;

  for (int i = 0; i < 4; ++i)
    for (int j = 0; j < 4; ++j)
      acc[i][j] = (floatx4){0.f, 0.f, 0.f, 0.f};

  for (int k0 = 0; k0 < EMB; k0 += 64) {
    for (int i = 0; i < 4; ++i) {
      const u16* ga = X + (size_t)(m0 + srow + i * 8) * EMB + k0 + scol;
      const u16* gb = W + (size_t)(n0 + srow + i * 8) * EMB + k0 + scol;
      u16* la = As + (wave * 4 + i) * 512;
      u16* lb = Bs + (wave * 4 + i) * 512;
      __builtin_amdgcn_global_load_lds(
          (__attribute__((address_space(1))) void*)ga,
          (__attribute__((address_space(3))) void*)la, 16, 0, 0);
      __builtin_amdgcn_global_load_lds(
          (__attribute__((address_space(1))) void*)gb,
          (__attribute__((address_space(3))) void*)lb, 16, 0, 0);
    }
    __syncthreads();
    for (int kc = 0; kc < 2; ++kc) {
      frag8 af[4], bfr[4];
      for (int i = 0; i < 4; ++i)
        af[i] = *reinterpret_cast<const frag8*>(
            As + (wr + i * 16 + l15) * 64 + kc * 32 + quad * 8);
      for (int j = 0; j < 4; ++j)
        bfr[j] = *reinterpret_cast<const frag8*>(
            Bs + (wc + j * 16 + l15) * 64 + kc * 32 + quad * 8);
      for (int i = 0; i < 4; ++i)
        for (int j = 0; j < 4; ++j)
          acc[i][j] = __builtin_amdgcn_mfma_f32_16x16x32_bf16(
              af[i], bfr[j], acc[i][j], 0, 0, 0);
    }
    __syncthreads();
  }
}

// ---------------------------------------------------------------------------
// K1: QKV projections. z=0 -> Q (scaled), z=1 -> K, z=2 -> Vt[bh][d][t].
//
// Epilogue rewritten to kill scattered/scalar global stores:
//  - z<2 : C-frags -> LDS [m][n] (stride 136, XOR key quad<<4 on bits 4-5 of
//          n -> conflict-free ds_write_u16), then 8x frag8 coalesced stores
//          per thread (256 B-contiguous per 16 lanes).
//  - z==2: C-frags packed u16x4 along t -> LDS TRANSPOSED [d][t] (stride 136),
//          then 8x frag8 stores with lanes covering contiguous t-runs.
//          (Old path: 8 B/lane at 2 KB stride = ~8x write amplification.)
// ---------------------------------------------------------------------------
__global__ __launch_bounds__(256, 3)
void qkv_kernel(const u16* __restrict__ X,
                const u16* __restrict__ Wqb, const float* __restrict__ bq,
                const u16* __restrict__ Wkb, const float* __restrict__ bk,
                const u16* __restrict__ Wvb, const float* __restrict__ bv,
                u16* __restrict__ Qs, u16* __restrict__ Ks, u16* __restrict__ Vt)
{
  __shared__ __align__(16) u16 SM[128 * 136];   // 34 KB; mainloop uses 32 KB
  u16* As = SM;
  u16* Bs = SM + 128 * 64;
  const int z  = blockIdx.z;
  const u16*   W  = (z == 0) ? Wqb : (z == 1) ? Wkb : Wvb;
  const float* bb = (z == 0) ? bq  : (z == 1) ? bk  : bv;
  const int m0 = blockIdx.y * 128;
  const int n0 = blockIdx.x * 128;

  floatx4 acc[4][4];
  gemm_mainloop(X, W, m0, n0, As, Bs, acc);

  const int tid  = threadIdx.x;
  const int lane = tid & 63, l15 = lane & 15, quad = lane >> 4;
  const int wave = tid >> 6;
  const int wr = (wave >> 1) * 64, wc = (wave & 1) * 64;
  // mainloop ended with __syncthreads(); SM is free for repacking

  if (z == 2) {
    // ---- write transposed tile T[d][t] (u16x4 packed along t)
    for (int j = 0; j < 4; ++j) {
      const int dl = wc + j * 16 + l15;            // local col (d) 0..127
      const float bn = bb[n0 + dl];
      for (int i = 0; i < 4; ++i) {
        const int tb = wr + i * 16 + quad * 4;     // local row (t) base
        u16x4 pk;
        for (int r = 0; r < 4; ++r) pk[r] = f2bf(acc[i][j][r] + bn);
        *reinterpret_cast<u16x4*>(SM + dl * 136 + tb) = pk;
      }
    }
    __syncthreads();
    const int b  = m0 >> 10;
    const int tg = m0 & 1023;
    const int h0 = n0 >> 6;
    for (int p = 0; p < 8; ++p) {
      const int dl = p * 16 + (tid >> 4);
      const int ch = tid & 15;
      frag8 vv = *reinterpret_cast<const frag8*>(SM + dl * 136 + ch * 8);
      const int h = h0 + (dl >> 6), d = dl & 63;
      *reinterpret_cast<frag8*>(
          Vt + ((size_t)((b * NH + h) * HD + d)) * SEQ + tg + ch * 8) = vv;
    }
  } else {
    const float sc = (z == 0) ? kScaling : 1.0f;
    u16* dst = (z == 0) ? Qs : Ks;
    // ---- write tile [m][n], XOR key = quad<<4 (bijective on n bits 4-5)
    for (int j = 0; j < 4; ++j) {
      const int n  = wc + j * 16 + l15;
      const float bn = bb[n0 + n];
      const int nx = n ^ (quad << 4);
      for (int i = 0; i < 4; ++i) {
        const int mb = wr + i * 16 + quad * 4;
        for (int r = 0; r < 4; ++r)
          SM[(mb + r) * 136 + nx] = f2bf((acc[i][j][r] + bn) * sc);
      }
    }
    __syncthreads();
    for (int p = 0; p < 8; ++p) {
      const int row = p * 16 + (tid >> 4);
      const int ch  = tid & 15;
      const int key = ((row >> 2) & 3) << 4;       // == quad of the writer
      frag8 vv = *reinterpret_cast<const frag8*>(
          SM + row * 136 + ((ch * 8) ^ key));
      *reinterpret_cast<frag8*>(
          dst + (size_t)(m0 + row) * EMB + n0 + ch * 8) = vv;
    }
  }
}

// ---------------------------------------------------------------------------
// K2: attention per (b,h). 64 q-rows/block (16/wave, 4 waves), 64-key tiles,
// grid (64,16) = 1024 blocks = 4/CU (LDS 40 KB/block).
//
// T3-minimum 2-phase pipeline: K/V double-buffered in LDS; tile t+1's stage
// (global_load_lds) AND bias register-prefetch issued at the TOP of tile t.
// No-max softmax (scores bounded; fp32 exp headroom). Pbuf XOR-swizzled.
// Epilogue: ctx repacked through Pbuf (free at that point) -> frag8 stores
// (was 16 scalar 2-B stores/thread at 32 B/row -> 2x write amplification).
// ---------------------------------------------------------------------------
__global__ __launch_bounds__(256, 4)
void attn_kernel(const u16* __restrict__ Qs, const u16* __restrict__ Ks,
                 const u16* __restrict__ Vt, const float* __restrict__ bias,
                 u16* __restrict__ ctx)
{
  __shared__ __align__(16) u16 Kt[2][64 * 64];   // 16 KB
  __shared__ __align__(16) u16 Vs[2][64 * 64];   // 16 KB
  __shared__ __align__(16) u16 Pbuf[64 * 64];    // 8 KB, XOR-swizzled
  const int bh = blockIdx.x;
  const int b  = bh >> 4;
  const int h  = bh & 15;
  const int t0 = blockIdx.y * 64;
  const int tid  = threadIdx.x;
  const int wave = tid >> 6;
  const int lane = tid & 63;
  const int l15 = lane & 15, quad = lane >> 4;
  const int wrow = t0 + wave * 16;
  const int srow = wave * 16 + (lane >> 3);   // staging row (+ i*8)
  const int scol = (lane & 7) * 8;

  // Q A-frags (A[m=l15][k=quad*8+j]) held in registers for the whole kernel
  frag8 qf[2];
  for (int kc = 0; kc < 2; ++kc)
    qf[kc] = *reinterpret_cast<const frag8*>(
        Qs + (size_t)(b * SEQ + wrow + l15) * EMB + h * HD + kc * 32 + quad * 8);

  floatx4 O[4];
  for (int df = 0; df < 4; ++df) O[df] = (floatx4){0.f, 0.f, 0.f, 0.f};
  float rs[4] = {0.f, 0.f, 0.f, 0.f};

  const float* bline = bias + ((size_t)bh * SEQ + wrow + quad * 4) * SEQ + l15;
  const u16* gk_base = Ks + (size_t)(b * SEQ + srow) * EMB + h * HD + scol;
  const u16* gv_base = Vt + ((size_t)bh * HD + srow) * SEQ + scol;

  // ---- prologue: stage tile 0 into buffer 0; prefetch bias tile 0
  for (int i = 0; i < 2; ++i) {
    __builtin_amdgcn_global_load_lds(
        (__attribute__((address_space(1))) void*)(gk_base + (size_t)i * 8 * EMB),
        (__attribute__((address_space(3))) void*)(Kt[0] + (wave * 2 + i) * 512),
        16, 0, 0);
    __builtin_amdgcn_global_load_lds(
        (__attribute__((address_space(1))) void*)(gv_base + i * 8 * SEQ),
        (__attribute__((address_space(3))) void*)(Vs[0] + (wave * 2 + i) * 512),
        16, 0, 0);
  }
  float bc[4][4], bn[4][4];
  for (int nf = 0; nf < 4; ++nf)
    for (int r = 0; r < 4; ++r)
      bc[nf][r] = __builtin_nontemporal_load(bline + (size_t)r * SEQ + nf * 16);
  __syncthreads();   // tile 0 resident

  for (int t = 0; t < 16; ++t) {
    const int c  = t & 1;
    const int s0 = t * 64;

    // ---- issue NEXT tile's stage + bias prefetch (consumed next iteration)
    if (t < 15) {
      const int sn = s0 + 64;
      for (int i = 0; i < 2; ++i) {
        __builtin_amdgcn_global_load_lds(
            (__attribute__((address_space(1))) void*)
                (gk_base + (size_t)(sn + i * 8) * EMB),
            (__attribute__((address_space(3))) void*)
                (Kt[c ^ 1] + (wave * 2 + i) * 512),
            16, 0, 0);
        __builtin_amdgcn_global_load_lds(
            (__attribute__((address_space(1))) void*)
                (gv_base + i * 8 * SEQ + sn),
            (__attribute__((address_space(3))) void*)
                (Vs[c ^ 1] + (wave * 2 + i) * 512),
            16, 0, 0);
      }
      for (int nf = 0; nf < 4; ++nf)
        for (int r = 0; r < 4; ++r)
          bn[nf][r] = __builtin_nontemporal_load(
              bline + (size_t)r * SEQ + sn + nf * 16);
    }

    // ---- S = Q K^T  (reads Kt[c])
    floatx4 S[4];
    __builtin_amdgcn_s_setprio(1);
    for (int nf = 0; nf < 4; ++nf) {
      frag8 k0f = *reinterpret_cast<const frag8*>(
          Kt[c] + (nf * 16 + l15) * 64 + quad * 8);
      frag8 k1f = *reinterpret_cast<const frag8*>(
          Kt[c] + (nf * 16 + l15) * 64 + 32 + quad * 8);
      floatx4 a0 = __builtin_amdgcn_mfma_f32_16x16x32_bf16(
          qf[0], k0f, (floatx4){0.f, 0.f, 0.f, 0.f}, 0, 0, 0);
      S[nf] = __builtin_amdgcn_mfma_f32_16x16x32_bf16(qf[1], k1f, a0, 0, 0, 0);
    }
    __builtin_amdgcn_s_setprio(0);

    // ---- p = exp(s + c*bias) using the prefetched bias registers
    for (int nf = 0; nf < 4; ++nf)
      for (int r = 0; r < 4; ++r) {
        const float p = __expf(fmaf(kAttnConst, bc[nf][r], S[nf][r]));
        rs[r] += p;
        Pbuf[(wave * 16 + quad * 4 + r) * 64 + ((nf * 16 + l15) ^ (quad << 4))] =
            f2bf(p);
      }
    if (t < 15)
      for (int nf = 0; nf < 4; ++nf)
        for (int r = 0; r < 4; ++r) bc[nf][r] = bn[nf][r];
    asm volatile("s_waitcnt lgkmcnt(0)" ::: "memory");  // wave-private P ready

    // ---- O += P @ V  (reads Vs[c]; readback applies the same per-row XOR)
    frag8 pa[2];
    for (int sc = 0; sc < 2; ++sc)
      pa[sc] = *reinterpret_cast<const frag8*>(
          Pbuf + (wave * 16 + l15) * 64 +
          ((sc * 32 + quad * 8) ^ ((l15 >> 2) << 4)));
    __builtin_amdgcn_s_setprio(1);
    for (int df = 0; df < 4; ++df) {
      frag8 v0f = *reinterpret_cast<const frag8*>(
          Vs[c] + (df * 16 + l15) * 64 + quad * 8);
      frag8 v1f = *reinterpret_cast<const frag8*>(
          Vs[c] + (df * 16 + l15) * 64 + 32 + quad * 8);
      O[df] = __builtin_amdgcn_mfma_f32_16x16x32_bf16(pa[0], v0f, O[df], 0, 0, 0);
      O[df] = __builtin_amdgcn_mfma_f32_16x16x32_bf16(pa[1], v1f, O[df], 0, 0, 0);
    }
    __builtin_amdgcn_s_setprio(0);
    // drain: next-tile stage landed in buf[c^1]; all waves done reading buf[c]
    __syncthreads();
  }

  // ---- single cross-lane reduce of row sums (over the 16 cols per quad)
  for (int d = 1; d < 16; d <<= 1)
    for (int r = 0; r < 4; ++r)
      rs[r] += __shfl_xor(rs[r], d);

  // ---- epilogue: repack O/rs through Pbuf (free), coalesced frag8 stores.
  // Write: rows trel = wave*16+quad*4+r, cols d = df*16+l15, XOR key quad<<4.
  for (int df = 0; df < 4; ++df)
    for (int r = 0; r < 4; ++r)
      Pbuf[(wave * 16 + quad * 4 + r) * 64 + ((df * 16 + l15) ^ (quad << 4))] =
          f2bf(O[df][r] / rs[r]);
  __syncthreads();
  for (int p = 0; p < 2; ++p) {
    const int row = p * 32 + (tid >> 3);
    const int ch  = tid & 7;
    const int key = ((row >> 2) & 3) << 4;
    frag8 vv = *reinterpret_cast<const frag8*>(
        Pbuf + row * 64 + ((ch * 8) ^ key));
    *reinterpret_cast<frag8*>(
        ctx + ((size_t)(b * SEQ + t0 + row)) * EMB + h * HD + ch * 8) = vv;
  }
}

// ---------------------------------------------------------------------------
// K3: out = ctx @ Wo^T + bo  (fp32 out). BM=64 x BN=128 -> 512 blocks.
// ---------------------------------------------------------------------------
__global__ __launch_bounds__(256, 4)
void proj_kernel(const u16* __restrict__ X, const u16* __restrict__ Wob,
                 const float* __restrict__ bo, float* __restrict__ out)
{
  __shared__ __align__(16) u16 As[64 * 64];
  __shared__ __align__(16) u16 Bs[128 * 64];
  const int m0 = blockIdx.y * 64;
  const int n0 = blockIdx.x * 128;

  const int tid  = threadIdx.x;
  const int wave = tid >> 6;
  const int lane = tid & 63;
  const int l15  = lane & 15;
  const int quad = lane >> 4;
  const int wr   = (wave >> 1) * 32;          // 2x2 waves of 32x64
  const int wc   = (wave & 1) * 64;
  const int srowA = wave * 16 + (lane >> 3);  // + i*8, i<2
  const int srowB = wave * 32 + (lane >> 3);  // + i*8, i<4
  const int scol  = (lane & 7) * 8;

  floatx4 acc[2][4];
  for (int i = 0; i < 2; ++i)
    for (int j = 0; j < 4; ++j)
      acc[i][j] = (floatx4){0.f, 0.f, 0.f, 0.f};

  for (int k0 = 0; k0 < EMB; k0 += 64) {
    for (int i = 0; i < 2; ++i) {
      const u16* ga = X + (size_t)(m0 + srowA + i * 8) * EMB + k0 + scol;
      __builtin_amdgcn_global_load_lds(
          (__attribute__((address_space(1))) void*)ga,
          (__attribute__((address_space(3))) void*)(As + (wave * 2 + i) * 512),
          16, 0, 0);
    }
    for (int i = 0; i < 4; ++i) {
      const u16* gb = Wob + (size_t)(n0 + srowB + i * 8) * EMB + k0 + scol;
      __builtin_amdgcn_global_load_lds(
          (__attribute__((address_space(1))) void*)gb,
          (__attribute__((address_space(3))) void*)(Bs + (wave * 4 + i) * 512),
          16, 0, 0);
    }
    __syncthreads();
    for (int kc = 0; kc < 2; ++kc) {
      frag8 af[2], bfr[4];
      for (int i = 0; i < 2; ++i)
        af[i] = *reinterpret_cast<const frag8*>(
            As + (wr + i * 16 + l15) * 64 + kc * 32 + quad * 8);
      for (int j = 0; j < 4; ++j)
        bfr[j] = *reinterpret_cast<const frag8*>(
            Bs + (wc + j * 16 + l15) * 64 + kc * 32 + quad * 8);
      for (int i = 0; i < 2; ++i)
        for (int j = 0; j < 4; ++j)
          acc[i][j] = __builtin_amdgcn_mfma_f32_16x16x32_bf16(
              af[i], bfr[j], acc[i][j], 0, 0, 0);
    }
    __syncthreads();
  }

  for (int j = 0; j < 4; ++j) {
    const int   n  = n0 + wc + j * 16 + l15;
    const float bn = bo[n];
    for (int i = 0; i < 2; ++i) {
      const int mbase = m0 + wr + i * 16 + quad * 4;
      for (int r = 0; r < 4; ++r)
        out[(size_t)(mbase + r) * EMB + n] = acc[i][j][r] + bn;
    }
  }
}

// ---------------------------------------------------------------------------
extern "C" void kernel_launch(void* const* d_in, const int* in_sizes, int n_in,
                              void* d_out, int out_size, void* d_ws, size_t ws_size,
                              hipStream_t stream)
{
  const float* hidden = (const float*)d_in[0];
  const float* attn_b = (const float*)d_in[1];
  const float* Wq = (const float*)d_in[2];
  const float* bq = (const float*)d_in[3];
  const float* Wk = (const float*)d_in[4];
  const float* bk = (const float*)d_in[5];
  const float* Wv = (const float*)d_in[6];
  const float* bv = (const float*)d_in[7];
  const float* Wo = (const float*)d_in[8];
  const float* bo = (const float*)d_in[9];
  float* out = (float*)d_out;

  const size_t MAT = (size_t)BSZ * SEQ * EMB;   // 4M elems
  const size_t WN  = (size_t)EMB * EMB;         // 1M elems
  u16* Qs  = (u16*)d_ws;
  u16* Ks  = Qs + MAT;
  u16* Vt  = Ks + MAT;
  u16* ctx = Vt + MAT;
  u16* Xb  = ctx + MAT;
  u16* Wqb = Xb + MAT;
  u16* Wkb = Wqb + WN;
  u16* Wvb = Wkb + WN;
  u16* Wob = Wvb + WN;            // total 24M u16 = 48 MB

  cvt_kernel<<<8192, 256, 0, stream>>>(hidden, Wq, Wk, Wv, Wo,
                                       Xb, Wqb, Wkb, Wvb, Wob);
  qkv_kernel<<<dim3(8, 32, 3), 256, 0, stream>>>(Xb, Wqb, bq, Wkb, bk, Wvb, bv,
                                                 Qs, Ks, Vt);
  attn_kernel<<<dim3(64, 16), 256, 0, stream>>>(Qs, Ks, Vt, attn_b, ctx);
  proj_kernel<<<dim3(8, 64), 256, 0, stream>>>(ctx, Wob, bo, out);
}